// Round 1
// baseline (1524.834 us; speedup 1.0000x reference)
//
#include <hip/hip_runtime.h>

#define N_NODES 100000
#define N_EDGES 1600000
// channels: layer1 in/out = 32; layer2 combined out = 16(mu)+16(lv) = 32

// ---------------- init: deg = 1.0 (self loop), acc = 0 ----------------
__global__ __launch_bounds__(256) void k_init(float* __restrict__ deg,
                                              float* __restrict__ acc) {
    int i = blockIdx.x * 256 + threadIdx.x;
    if (i < N_NODES) deg[i] = 1.0f;
    if (i < N_NODES * 32) acc[i] = 0.0f;
}

// ---------------- degree histogram over dst ----------------
__global__ __launch_bounds__(256) void k_deg(const int* __restrict__ dst,
                                             float* __restrict__ deg) {
    int e = blockIdx.x * 256 + threadIdx.x;
    if (e < N_EDGES) atomicAdd(&deg[dst[e]], 1.0f);
}

// ---------------- deg -> rsqrt(deg), in place ----------------
__global__ __launch_bounds__(256) void k_rsqrt(float* __restrict__ deg) {
    int i = blockIdx.x * 256 + threadIdx.x;
    if (i < N_NODES) deg[i] = rsqrtf(deg[i]);   // deg >= 1 always (self loop)
}

// ---------------- p = dinv * (x @ W1), W1 [32,32] row-major ----------------
// 32 lanes per node; lane = output channel; x row broadcast via shfl.
__global__ __launch_bounds__(256) void k_xform1(const float* __restrict__ x,
                                                const float* __restrict__ W,
                                                const float* __restrict__ dinv,
                                                float* __restrict__ p) {
    __shared__ float sW[32 * 32];
    int tid = threadIdx.x;
    for (int i = tid; i < 1024; i += 256) sW[i] = W[i];
    __syncthreads();
    int lane = tid & 31;
    int node = blockIdx.x * 8 + (tid >> 5);
    if (node >= N_NODES) return;
    float xv = x[node * 32 + lane];
    float a = 0.f;
#pragma unroll
    for (int k = 0; k < 32; ++k) {
        float xk = __shfl(xv, k, 32);
        a += xk * sW[k * 32 + lane];
    }
    p[node * 32 + lane] = dinv[node] * a;
}

// ---------------- scatter: acc[dst] += p[src], 32 channels/edge ----------------
// thread = (edge, 4 channels): float4 gather + 4 scalar atomics (contiguous).
__global__ __launch_bounds__(256) void k_scatter(const int* __restrict__ src,
                                                 const int* __restrict__ dst,
                                                 const float* __restrict__ p,
                                                 float* __restrict__ acc) {
    int idx = blockIdx.x * 256 + threadIdx.x;
    int e = idx >> 3;
    if (e >= N_EDGES) return;
    int c4 = (idx & 7) << 2;
    int s = src[e], d = dst[e];
    const float4 v = *(const float4*)(p + s * 32 + c4);
    float* a = acc + d * 32 + c4;
    atomicAdd(a + 0, v.x);
    atomicAdd(a + 1, v.y);
    atomicAdd(a + 2, v.z);
    atomicAdd(a + 3, v.w);
}

// ---------------- layer-1 finalize + layer-2 transform (fused) ----------------
// h = relu(dinv*(acc + p) + b1)        [self-loop contributes p analytically]
// p <- dinv * (h @ [Wmu || Wlv])       (in-place over p; per-lane read-then-write)
__global__ __launch_bounds__(256) void k_xform2(const float* __restrict__ acc,
                                                const float* __restrict__ b1,
                                                const float* __restrict__ Wmu,
                                                const float* __restrict__ Wlv,
                                                const float* __restrict__ dinv,
                                                float* __restrict__ p) {
    __shared__ float sW[32 * 32];
    __shared__ float sB[32];
    int tid = threadIdx.x;
    for (int i = tid; i < 1024; i += 256) {
        int k = i >> 5, oc = i & 31;
        sW[i] = (oc < 16) ? Wmu[k * 16 + oc] : Wlv[k * 16 + (oc - 16)];
    }
    if (tid < 32) sB[tid] = b1[tid];
    __syncthreads();
    int lane = tid & 31;
    int node = blockIdx.x * 8 + (tid >> 5);
    if (node >= N_NODES) return;
    float di = dinv[node];
    float h = di * (acc[node * 32 + lane] + p[node * 32 + lane]) + sB[lane];
    h = fmaxf(h, 0.f);
    float a = 0.f;
#pragma unroll
    for (int k = 0; k < 32; ++k) {
        float hk = __shfl(h, k, 32);
        a += hk * sW[k * 32 + lane];
    }
    p[node * 32 + lane] = di * a;
}

// ---------------- zero acc between scatter passes ----------------
__global__ __launch_bounds__(256) void k_zero(float* __restrict__ acc) {
    int i = blockIdx.x * 256 + threadIdx.x;
    if (i < N_NODES * 32) acc[i] = 0.0f;
}

// ---------------- finalize: mu / logvar, split + bias ----------------
__global__ __launch_bounds__(256) void k_final(const float* __restrict__ acc,
                                               const float* __restrict__ p,
                                               const float* __restrict__ dinv,
                                               const float* __restrict__ bmu,
                                               const float* __restrict__ blv,
                                               float* __restrict__ out) {
    int tid = threadIdx.x;
    int lane = tid & 31;
    int node = blockIdx.x * 8 + (tid >> 5);
    if (node >= N_NODES) return;
    float di = dinv[node];
    float v = di * (acc[node * 32 + lane] + p[node * 32 + lane]);
    if (lane < 16) {
        out[node * 16 + lane] = v + bmu[lane];
    } else {
        out[N_NODES * 16 + node * 16 + (lane - 16)] = v + blv[lane - 16];
    }
}

extern "C" void kernel_launch(void* const* d_in, const int* in_sizes, int n_in,
                              void* d_out, int out_size, void* d_ws, size_t ws_size,
                              hipStream_t stream) {
    const float* x   = (const float*)d_in[0];
    const int*   ei  = (const int*)d_in[1];
    const float* W1  = (const float*)d_in[2];
    const float* b1  = (const float*)d_in[3];
    const float* Wmu = (const float*)d_in[4];
    const float* bmu = (const float*)d_in[5];
    const float* Wlv = (const float*)d_in[6];
    const float* blv = (const float*)d_in[7];
    float* out = (float*)d_out;

    const int* src = ei;            // edge_index[0]
    const int* dst = ei + N_EDGES;  // edge_index[1]

    // workspace layout (floats): deg/dinv [N] | p [N*32] | acc [N*32]  (~26 MB)
    float* deg = (float*)d_ws;
    float* p   = deg + N_NODES;
    float* acc = p + N_NODES * 32;

    const int nodeBlocks = (N_NODES + 7) / 8;            // 12500 (8 nodes/block)
    const int accBlocks  = (N_NODES * 32 + 255) / 256;   // 12500
    const int edgeBlocks = (N_EDGES + 255) / 256;        // 6250
    const int scatBlocks = (N_EDGES * 8 + 255) / 256;    // 50000

    k_init  <<<accBlocks, 256, 0, stream>>>(deg, acc);
    k_deg   <<<edgeBlocks, 256, 0, stream>>>(dst, deg);
    k_rsqrt <<<(N_NODES + 255) / 256, 256, 0, stream>>>(deg);
    k_xform1<<<nodeBlocks, 256, 0, stream>>>(x, W1, deg, p);
    k_scatter<<<scatBlocks, 256, 0, stream>>>(src, dst, p, acc);
    k_xform2<<<nodeBlocks, 256, 0, stream>>>(acc, b1, Wmu, Wlv, deg, p);
    k_zero  <<<accBlocks, 256, 0, stream>>>(acc);
    k_scatter<<<scatBlocks, 256, 0, stream>>>(src, dst, p, acc);
    k_final <<<nodeBlocks, 256, 0, stream>>>(acc, p, deg, bmu, blv, out);
}

// Round 2
// 435.060 us; speedup vs baseline: 3.5049x; 3.5049x over previous
//
#include <hip/hip_runtime.h>

#define N_NODES 100000
#define N_EDGES 1600000
#define SCAN_BLOCKS 391  // ceil((N_NODES+1)/256)

// ---------------- zero int counts ----------------
__global__ __launch_bounds__(256) void k_zero_counts(int* __restrict__ counts) {
    int i = blockIdx.x * 256 + threadIdx.x;
    if (i < N_NODES) counts[i] = 0;
}

// ---------------- degree histogram over dst (int) ----------------
__global__ __launch_bounds__(256) void k_hist(const int* __restrict__ dst,
                                              int* __restrict__ counts) {
    int e = blockIdx.x * 256 + threadIdx.x;
    if (e < N_EDGES) atomicAdd(&counts[dst[e]], 1);
}

// ---------------- scan phase A: per-block sums ----------------
__global__ __launch_bounds__(256) void k_scanA(const int* __restrict__ counts,
                                               int* __restrict__ blockSums) {
    __shared__ int s[256];
    int i = blockIdx.x * 256 + threadIdx.x;
    s[threadIdx.x] = (i < N_NODES) ? counts[i] : 0;
    __syncthreads();
    for (int off = 128; off > 0; off >>= 1) {
        if (threadIdx.x < off) s[threadIdx.x] += s[threadIdx.x + off];
        __syncthreads();
    }
    if (threadIdx.x == 0) blockSums[blockIdx.x] = s[0];
}

// ---------------- scan phase B: exclusive scan of block sums (1 block) ----------------
__global__ __launch_bounds__(512) void k_scanB(int* __restrict__ blockSums) {
    __shared__ int s[512];
    int t = threadIdx.x;
    s[t] = (t < SCAN_BLOCKS) ? blockSums[t] : 0;
    __syncthreads();
    for (int off = 1; off < 512; off <<= 1) {
        int v = (t >= off) ? s[t - off] : 0;
        __syncthreads();
        s[t] += v;
        __syncthreads();
    }
    if (t < SCAN_BLOCKS) blockSums[t] = (t > 0) ? s[t - 1] : 0;
}

// ---------------- scan phase C: rowStart/cursor/dinv ----------------
__global__ __launch_bounds__(256) void k_scanC(const int* __restrict__ counts,
                                               const int* __restrict__ blockOff,
                                               int* __restrict__ rowStart,
                                               int* __restrict__ cursor,
                                               float* __restrict__ dinv) {
    __shared__ int s[256];
    int i = blockIdx.x * 256 + threadIdx.x;
    int v = (i < N_NODES) ? counts[i] : 0;
    s[threadIdx.x] = v;
    __syncthreads();
    for (int off = 1; off < 256; off <<= 1) {
        int t = (threadIdx.x >= off) ? s[threadIdx.x - off] : 0;
        __syncthreads();
        s[threadIdx.x] += t;
        __syncthreads();
    }
    int excl = (threadIdx.x > 0) ? s[threadIdx.x - 1] : 0;
    int start = blockOff[blockIdx.x] + excl;
    if (i <= N_NODES) {
        rowStart[i] = start;
        if (i < N_NODES) {
            cursor[i] = start;
            dinv[i] = rsqrtf((float)(v + 1));  // +1 = self loop
        }
    }
}

// ---------------- fill CSR: srcSorted grouped by dst ----------------
__global__ __launch_bounds__(256) void k_fill(const int* __restrict__ src,
                                              const int* __restrict__ dst,
                                              int* __restrict__ cursor,
                                              int* __restrict__ srcSorted) {
    int e = blockIdx.x * 256 + threadIdx.x;
    if (e < N_EDGES) {
        int pos = atomicAdd(&cursor[dst[e]], 1);
        srcSorted[pos] = src[e];
    }
}

// ---------------- p = dinv * (x @ W1) ----------------
__global__ __launch_bounds__(256) void k_xform1(const float* __restrict__ x,
                                                const float* __restrict__ W,
                                                const float* __restrict__ dinv,
                                                float* __restrict__ p) {
    __shared__ float sW[32 * 32];
    int tid = threadIdx.x;
    for (int i = tid; i < 1024; i += 256) sW[i] = W[i];
    __syncthreads();
    int lane = tid & 31;
    int node = blockIdx.x * 8 + (tid >> 5);
    if (node >= N_NODES) return;
    float xv = x[node * 32 + lane];
    float a = 0.f;
#pragma unroll
    for (int k = 0; k < 32; ++k) {
        float xk = __shfl(xv, k, 32);
        a += xk * sW[k * 32 + lane];
    }
    p[node * 32 + lane] = dinv[node] * a;
}

// ---------------- gather layer 1 + relu + layer-2 transform (fused) ----------------
__global__ __launch_bounds__(256) void k_gx2(const int* __restrict__ rowStart,
                                             const int* __restrict__ srcSorted,
                                             const float* __restrict__ p,
                                             const float* __restrict__ dinv,
                                             const float* __restrict__ b1,
                                             const float* __restrict__ Wmu,
                                             const float* __restrict__ Wlv,
                                             float* __restrict__ p2) {
    __shared__ float sW[32 * 32];
    __shared__ float sB[32];
    int tid = threadIdx.x;
    for (int i = tid; i < 1024; i += 256) {
        int k = i >> 5, oc = i & 31;
        sW[i] = (oc < 16) ? Wmu[k * 16 + oc] : Wlv[k * 16 + (oc - 16)];
    }
    if (tid < 32) sB[tid] = b1[tid];
    __syncthreads();
    int lane = tid & 31;
    int node = blockIdx.x * 8 + (tid >> 5);
    if (node >= N_NODES) return;
    int beg = rowStart[node], end = rowStart[node + 1];
    float a = 0.f;
    for (int base = beg; base < end; base += 32) {
        int idx = base + lane;
        int myS = (idx < end) ? srcSorted[idx] : 0;
        int n = end - base; if (n > 32) n = 32;
        for (int j = 0; j < n; ++j) {
            int s = __shfl(myS, j, 32);
            a += p[s * 32 + lane];
        }
    }
    float di = dinv[node];
    float h = fmaxf(di * (a + p[node * 32 + lane]) + sB[lane], 0.f);  // self loop = p[node]
    float o = 0.f;
#pragma unroll
    for (int k = 0; k < 32; ++k) {
        float hk = __shfl(h, k, 32);
        o += hk * sW[k * 32 + lane];
    }
    p2[node * 32 + lane] = di * o;
}

// ---------------- gather layer 2 + mu/logvar epilogue ----------------
__global__ __launch_bounds__(256) void k_gfin(const int* __restrict__ rowStart,
                                              const int* __restrict__ srcSorted,
                                              const float* __restrict__ p2,
                                              const float* __restrict__ dinv,
                                              const float* __restrict__ bmu,
                                              const float* __restrict__ blv,
                                              float* __restrict__ out) {
    int tid = threadIdx.x;
    int lane = tid & 31;
    int node = blockIdx.x * 8 + (tid >> 5);
    if (node >= N_NODES) return;
    int beg = rowStart[node], end = rowStart[node + 1];
    float a = 0.f;
    for (int base = beg; base < end; base += 32) {
        int idx = base + lane;
        int myS = (idx < end) ? srcSorted[idx] : 0;
        int n = end - base; if (n > 32) n = 32;
        for (int j = 0; j < n; ++j) {
            int s = __shfl(myS, j, 32);
            a += p2[s * 32 + lane];
        }
    }
    float v = dinv[node] * (a + p2[node * 32 + lane]);
    if (lane < 16) {
        out[node * 16 + lane] = v + bmu[lane];
    } else {
        out[N_NODES * 16 + node * 16 + (lane - 16)] = v + blv[lane - 16];
    }
}

extern "C" void kernel_launch(void* const* d_in, const int* in_sizes, int n_in,
                              void* d_out, int out_size, void* d_ws, size_t ws_size,
                              hipStream_t stream) {
    const float* x   = (const float*)d_in[0];
    const int*   ei  = (const int*)d_in[1];
    const float* W1  = (const float*)d_in[2];
    const float* b1  = (const float*)d_in[3];
    const float* Wmu = (const float*)d_in[4];
    const float* bmu = (const float*)d_in[5];
    const float* Wlv = (const float*)d_in[6];
    const float* blv = (const float*)d_in[7];
    float* out = (float*)d_out;

    const int* src = ei;            // edge_index[0]
    const int* dst = ei + N_EDGES;  // edge_index[1]

    // workspace layout:
    // ints:   counts[N] | rowStart[N+1] | cursor[N] | blockSums[512] | srcSorted[E]
    // floats: dinv[N] | p1[N*32] | p2[N*32]                          (~34 MB total)
    int* counts    = (int*)d_ws;
    int* rowStart  = counts + N_NODES;
    int* cursor    = rowStart + N_NODES + 1;
    int* blockSums = cursor + N_NODES;
    int* srcSorted = blockSums + 512;
    float* dinv    = (float*)(srcSorted + N_EDGES);
    float* p1      = dinv + N_NODES;
    float* p2      = p1 + N_NODES * 32;

    const int nodeBlocks = (N_NODES + 7) / 8;          // 12500
    const int edgeBlocks = (N_EDGES + 255) / 256;      // 6250
    const int nBlocks    = (N_NODES + 255) / 256;      // 391

    k_zero_counts<<<nBlocks, 256, 0, stream>>>(counts);
    k_hist <<<edgeBlocks, 256, 0, stream>>>(dst, counts);
    k_scanA<<<SCAN_BLOCKS, 256, 0, stream>>>(counts, blockSums);
    k_scanB<<<1, 512, 0, stream>>>(blockSums);
    k_scanC<<<SCAN_BLOCKS, 256, 0, stream>>>(counts, blockSums, rowStart, cursor, dinv);
    k_fill <<<edgeBlocks, 256, 0, stream>>>(src, dst, cursor, srcSorted);
    k_xform1<<<nodeBlocks, 256, 0, stream>>>(x, W1, dinv, p1);
    k_gx2  <<<nodeBlocks, 256, 0, stream>>>(rowStart, srcSorted, p1, dinv, b1, Wmu, Wlv, p2);
    k_gfin <<<nodeBlocks, 256, 0, stream>>>(rowStart, srcSorted, p2, dinv, bmu, blv, out);
}

// Round 3
// 305.719 us; speedup vs baseline: 4.9877x; 1.4231x over previous
//
#include <hip/hip_runtime.h>

#define N_NODES 100000
#define N_EDGES 1600000
#define NB 391            // node buckets of 256: bucket = dst >> 8
#define PART_CHUNK 4096
#define PART_BLOCKS 391   // ceil(N_EDGES / PART_CHUNK)

// ---------------- zero bucket counts ----------------
__global__ __launch_bounds__(512) void k_bzero(int* __restrict__ bucketCnt) {
    int t = threadIdx.x;
    if (t < NB) bucketCnt[t] = 0;
}

// ---------------- bucket histogram (LDS-aggregated) ----------------
__global__ __launch_bounds__(256) void k_bhist(const int* __restrict__ dst,
                                               int* __restrict__ bucketCnt) {
    __shared__ int bh[NB];
    for (int i = threadIdx.x; i < NB; i += 256) bh[i] = 0;
    __syncthreads();
    int stride = gridDim.x * 256;
    for (int e = blockIdx.x * 256 + threadIdx.x; e < N_EDGES; e += stride)
        atomicAdd(&bh[((unsigned)dst[e]) >> 8], 1);
    __syncthreads();
    for (int i = threadIdx.x; i < NB; i += 256)
        if (bh[i] > 0) atomicAdd(&bucketCnt[i], bh[i]);
}

// ---------------- bucket exclusive scan (1 block) ----------------
__global__ __launch_bounds__(512) void k_bscan(const int* __restrict__ bucketCnt,
                                               int* __restrict__ bucketStart,
                                               int* __restrict__ bucketCursor) {
    __shared__ int s[512];
    int t = threadIdx.x;
    int v = (t < NB) ? bucketCnt[t] : 0;
    s[t] = v;
    __syncthreads();
    for (int off = 1; off < 512; off <<= 1) {
        int u = (t >= off) ? s[t - off] : 0;
        __syncthreads();
        s[t] += u;
        __syncthreads();
    }
    if (t < NB) {
        bucketStart[t + 1] = s[t];       // inclusive -> start of next
        bucketCursor[t] = s[t] - v;      // exclusive
    }
    if (t == 0) bucketStart[0] = 0;
}

// ---------------- partition edges into buckets (packed dstLow|src) ----------------
__global__ __launch_bounds__(256) void k_part(const int* __restrict__ src,
                                              const int* __restrict__ dst,
                                              int* __restrict__ bucketCursor,
                                              unsigned* __restrict__ packed) {
    __shared__ int bh[NB];
    __shared__ int base[NB];
    int t = threadIdx.x;
    for (int i = t; i < NB; i += 256) bh[i] = 0;
    __syncthreads();
    int e0 = blockIdx.x * PART_CHUNK;
    int e1 = e0 + PART_CHUNK; if (e1 > N_EDGES) e1 = N_EDGES;
    for (int e = e0 + t; e < e1; e += 256)
        atomicAdd(&bh[((unsigned)dst[e]) >> 8], 1);
    __syncthreads();
    for (int i = t; i < NB; i += 256) {
        int c = bh[i];
        base[i] = (c > 0) ? atomicAdd(&bucketCursor[i], c) : 0;
        bh[i] = 0;   // reuse as local rank counter
    }
    __syncthreads();
    for (int e = e0 + t; e < e1; e += 256) {
        unsigned d = (unsigned)dst[e];
        int b = d >> 8;
        int r = atomicAdd(&bh[b], 1);
        packed[base[b] + r] = ((d & 255u) << 24) | (unsigned)src[e];
    }
}

// ---------------- per-bucket: counts -> rowStart/dinv (local scan) + fill CSR ----------------
__global__ __launch_bounds__(256) void k_csr(const unsigned* __restrict__ packed,
                                             const int* __restrict__ bucketStart,
                                             int* __restrict__ rowStart,
                                             float* __restrict__ dinv,
                                             int* __restrict__ srcSorted) {
    __shared__ int cnt[256];
    __shared__ int s[256];
    __shared__ int cur[256];
    int t = threadIdx.x;
    int b = blockIdx.x;
    int seg0 = bucketStart[b], seg1 = bucketStart[b + 1];
    cnt[t] = 0;
    __syncthreads();
    for (int i = seg0 + t; i < seg1; i += 256)
        atomicAdd(&cnt[packed[i] >> 24], 1);
    __syncthreads();
    int v = cnt[t];
    s[t] = v;
    __syncthreads();
    for (int off = 1; off < 256; off <<= 1) {
        int u = (t >= off) ? s[t - off] : 0;
        __syncthreads();
        s[t] += u;
        __syncthreads();
    }
    int start = seg0 + s[t] - v;   // exclusive scan
    int node = b * 256 + t;
    if (node <= N_NODES) rowStart[node] = start;
    if (node < N_NODES) dinv[node] = rsqrtf((float)(v + 1));  // +1 self loop
    cur[t] = start;
    __syncthreads();
    for (int i = seg0 + t; i < seg1; i += 256) {
        unsigned pk = packed[i];
        int pos = atomicAdd(&cur[pk >> 24], 1);
        srcSorted[pos] = (int)(pk & 0xFFFFFFu);
    }
}

// ---------------- p = dinv * (x @ W1) ----------------
__global__ __launch_bounds__(256) void k_xform1(const float* __restrict__ x,
                                                const float* __restrict__ W,
                                                const float* __restrict__ dinv,
                                                float* __restrict__ p) {
    __shared__ float sW[32 * 32];
    int tid = threadIdx.x;
    for (int i = tid; i < 1024; i += 256) sW[i] = W[i];
    __syncthreads();
    int lane = tid & 31;
    int node = blockIdx.x * 8 + (tid >> 5);
    if (node >= N_NODES) return;
    float xv = x[node * 32 + lane];
    float a = 0.f;
#pragma unroll
    for (int k = 0; k < 32; ++k) {
        float xk = __shfl(xv, k, 32);
        a += xk * sW[k * 32 + lane];
    }
    p[node * 32 + lane] = dinv[node] * a;
}

// ---------------- gather layer 1 + relu + layer-2 transform (fused) ----------------
__global__ __launch_bounds__(256) void k_gx2(const int* __restrict__ rowStart,
                                             const int* __restrict__ srcSorted,
                                             const float* __restrict__ p,
                                             const float* __restrict__ dinv,
                                             const float* __restrict__ b1,
                                             const float* __restrict__ Wmu,
                                             const float* __restrict__ Wlv,
                                             float* __restrict__ p2) {
    __shared__ float sW[32 * 32];
    __shared__ float sB[32];
    int tid = threadIdx.x;
    for (int i = tid; i < 1024; i += 256) {
        int k = i >> 5, oc = i & 31;
        sW[i] = (oc < 16) ? Wmu[k * 16 + oc] : Wlv[k * 16 + (oc - 16)];
    }
    if (tid < 32) sB[tid] = b1[tid];
    __syncthreads();
    int lane = tid & 31;
    int node = blockIdx.x * 8 + (tid >> 5);
    if (node >= N_NODES) return;
    int beg = rowStart[node], end = rowStart[node + 1];
    float a = 0.f;
    for (int base = beg; base < end; base += 32) {
        int idx = base + lane;
        int myS = (idx < end) ? srcSorted[idx] : 0;
        int n = end - base; if (n > 32) n = 32;
        for (int j = 0; j < n; ++j) {
            int s = __shfl(myS, j, 32);
            a += p[s * 32 + lane];
        }
    }
    float di = dinv[node];
    float h = fmaxf(di * (a + p[node * 32 + lane]) + sB[lane], 0.f);  // self loop
    float o = 0.f;
#pragma unroll
    for (int k = 0; k < 32; ++k) {
        float hk = __shfl(h, k, 32);
        o += hk * sW[k * 32 + lane];
    }
    p2[node * 32 + lane] = di * o;
}

// ---------------- gather layer 2 + mu/logvar epilogue ----------------
__global__ __launch_bounds__(256) void k_gfin(const int* __restrict__ rowStart,
                                              const int* __restrict__ srcSorted,
                                              const float* __restrict__ p2,
                                              const float* __restrict__ dinv,
                                              const float* __restrict__ bmu,
                                              const float* __restrict__ blv,
                                              float* __restrict__ out) {
    int tid = threadIdx.x;
    int lane = tid & 31;
    int node = blockIdx.x * 8 + (tid >> 5);
    if (node >= N_NODES) return;
    int beg = rowStart[node], end = rowStart[node + 1];
    float a = 0.f;
    for (int base = beg; base < end; base += 32) {
        int idx = base + lane;
        int myS = (idx < end) ? srcSorted[idx] : 0;
        int n = end - base; if (n > 32) n = 32;
        for (int j = 0; j < n; ++j) {
            int s = __shfl(myS, j, 32);
            a += p2[s * 32 + lane];
        }
    }
    float v = dinv[node] * (a + p2[node * 32 + lane]);
    if (lane < 16) {
        out[node * 16 + lane] = v + bmu[lane];
    } else {
        out[N_NODES * 16 + node * 16 + (lane - 16)] = v + blv[lane - 16];
    }
}

extern "C" void kernel_launch(void* const* d_in, const int* in_sizes, int n_in,
                              void* d_out, int out_size, void* d_ws, size_t ws_size,
                              hipStream_t stream) {
    const float* x   = (const float*)d_in[0];
    const int*   ei  = (const int*)d_in[1];
    const float* W1  = (const float*)d_in[2];
    const float* b1  = (const float*)d_in[3];
    const float* Wmu = (const float*)d_in[4];
    const float* bmu = (const float*)d_in[5];
    const float* Wlv = (const float*)d_in[6];
    const float* blv = (const float*)d_in[7];
    float* out = (float*)d_out;

    const int* src = ei;            // edge_index[0]
    const int* dst = ei + N_EDGES;  // edge_index[1]

    // workspace layout:
    //  bucketCnt[NB] | bucketStart[NB+1] | bucketCursor[NB] | rowStart[N+1]
    //  | srcSorted[E] | dinv[N] | p1[N*32] | p2[N*32]
    // packed[E] (6.4MB) aliases the FRONT of p2 (12.8MB): packed is dead before
    // k_gx2 writes p2 (stream-ordered), keeping total ws at ~33 MB.
    int* bucketCnt    = (int*)d_ws;
    int* bucketStart  = bucketCnt + NB;
    int* bucketCursor = bucketStart + NB + 1;
    int* rowStart     = bucketCursor + NB;
    int* srcSorted    = rowStart + N_NODES + 1;
    float* dinv       = (float*)(srcSorted + N_EDGES);
    float* p1         = dinv + N_NODES;
    float* p2         = p1 + N_NODES * 32;
    unsigned* packed  = (unsigned*)p2;   // alias: dead before p2 is written

    const int nodeBlocks = (N_NODES + 7) / 8;  // 12500

    k_bzero<<<1, 512, 0, stream>>>(bucketCnt);
    k_bhist<<<512, 256, 0, stream>>>(dst, bucketCnt);
    k_bscan<<<1, 512, 0, stream>>>(bucketCnt, bucketStart, bucketCursor);
    k_part <<<PART_BLOCKS, 256, 0, stream>>>(src, dst, bucketCursor, packed);
    k_csr  <<<NB, 256, 0, stream>>>(packed, bucketStart, rowStart, dinv, srcSorted);
    k_xform1<<<nodeBlocks, 256, 0, stream>>>(x, W1, dinv, p1);
    k_gx2  <<<nodeBlocks, 256, 0, stream>>>(rowStart, srcSorted, p1, dinv, b1, Wmu, Wlv, p2);
    k_gfin <<<nodeBlocks, 256, 0, stream>>>(rowStart, srcSorted, p2, dinv, bmu, blv, out);
}